// Round 5
// baseline (232.107 us; speedup 1.0000x reference)
//
#include <hip/hip_runtime.h>
#include <hip/hip_bf16.h>

#define SL 2048
#define NK 24
#define NI 256
#define NO 256
#define NB 2
#define NC 48
#define TD 64

typedef __bf16 bf16x8 __attribute__((ext_vector_type(8)));
typedef float f32x4 __attribute__((ext_vector_type(4)));
typedef unsigned short u16x8 __attribute__((ext_vector_type(8)));
typedef unsigned short ushort_t;
typedef unsigned int u32;

// workspace layout (bytes)
// Toeplitz bank: 35 slots (slots 0..2 = zeros for d=-3..-1; slot s=d+3)
#define OFF_T   0ull
#define SZ_T    (35ull*48*64*64*2)
#define OFF_MT  (OFF_T + SZ_T)            // M_T [48][256][256] bf16 ([c][o][i])
#define SZ_MT   (48ull*256*256*2)
#define OFF_XB  (OFF_MT + SZ_MT)          // x bf16 [2][2048][256]
#define SZ_XB   (2ull*2048*256*2)
#define OFF_YT  (OFF_XB + SZ_XB)          // Y_T [2][48][256][2048] bf16 ([b][c][o][t])
#define SZ_YT   (2ull*48*256*2048*2)
#define WS_NEED (OFF_YT + SZ_YT)

__device__ __forceinline__ unsigned short f2bf(float f) {
    unsigned int u = __float_as_uint(f);
    unsigned int r = (u + 0x7FFFu + ((u >> 16) & 1u)) >> 16;
    return (unsigned short)r;
}

__device__ __forceinline__ void glds16(ushort_t* l, const ushort_t* g) {
    __builtin_amdgcn_global_load_lds((const __attribute__((address_space(1))) u32*)g,
                                     (__attribute__((address_space(3))) u32*)l, 16, 0, 0);
}

// ---- kernel 0a: x f32 -> bf16 -------------------------------------------
__global__ void k_cvt_x(const float* __restrict__ x, ushort_t* __restrict__ xb) {
    int i = blockIdx.x * blockDim.x + threadIdx.x;
    float4 v = reinterpret_cast<const float4*>(x)[i];
    ushort4 o;
    o.x = f2bf(v.x); o.y = f2bf(v.y); o.z = f2bf(v.z); o.w = f2bf(v.w);
    reinterpret_cast<ushort4*>(xb)[i] = o;
}

// ---- kernel 0b: M [k][i][o] f32 -> M_T [c][o][i] bf16 -------------------
__global__ void k_mt(const float* __restrict__ Mp, const float* __restrict__ Mm,
                     ushort_t* __restrict__ mt) {
    __shared__ float tile[64][65];
    int c = blockIdx.x, it = blockIdx.y, ot = blockIdx.z;
    int k = c >> 1;
    const float* M = (c & 1) ? Mm : Mp;
    int tid = threadIdx.x;
    int col = tid & 63, rq = tid >> 6;
    for (int rr = 0; rr < 64; rr += 4) {
        int i = rr + rq;
        tile[i][col] = M[((k * NI) + (it * 64 + i)) * NO + ot * 64 + col];
    }
    __syncthreads();
    for (int rr = 0; rr < 64; rr += 4) {
        int o = rr + rq;
        mt[((c * NO) + (ot * 64 + o)) * NI + it * 64 + col] = f2bf(tile[col][o]);
    }
}

// ---- kernel 1: Toeplitz bank, slot s=d+3: T[s][c][li][ti] = F[64d+li-ti, c]
__global__ void k_toep(const float* __restrict__ phi, ushort_t* __restrict__ T) {
    int d = (int)blockIdx.x - 3, c = blockIdx.y;
    int ti = threadIdx.x;
    int k = c >> 1, odd = c & 1;
    for (int li = 0; li < TD; ++li) {
        int s = d * TD + li - ti;
        float v = 0.f;
        if (s >= 0 && s < SL) {
            v = phi[s * NK + k];
            if (odd && (s & 1)) v = -v;
        }
        T[(((blockIdx.x) * NC + c) * TD + li) * TD + ti] = f2bf(v);
    }
}

// ---- kernel 2: Y_T[b][c][o][t] = sum_i x[b,t,i] * M_c[i,o] (known-good) --
__global__ __launch_bounds__(256, 3) void k_gemm1(const ushort_t* __restrict__ XB,
                                                  const ushort_t* __restrict__ MT,
                                                  ushort_t* __restrict__ yt) {
    __shared__ ushort_t sh[17408];
    int nb_ = blockIdx.x;
    int rb  = blockIdx.y;
    int n0 = nb_ * 128;
    int tid = threadIdx.x, lane = tid & 63, wid = tid >> 6;
    int wr = wid >> 1, wc = wid & 1;
    int ln15 = lane & 15, lq = lane >> 4;
    int swz = lq ^ ((ln15 >> 1) & 3);

    const ushort_t* Arow = XB + (size_t)(rb * 128) * 256;
    const ushort_t* Brow = MT + (size_t)n0 * 256;

    auto stage = [&](int bufsel, int s) {
        ushort_t* L = sh + bufsel * 8192;
        int k0 = s * 32;
#pragma unroll
        for (int jj = 0; jj < 2; ++jj) {
            int flat = tid + jj * 256;
            int row = flat >> 2;
            int k8s = (flat & 3) ^ ((flat >> 3) & 3);
            glds16(L + flat * 8, Arow + row * 256 + k0 + k8s * 8);
        }
#pragma unroll
        for (int jj = 0; jj < 2; ++jj) {
            int flat = tid + jj * 256;
            int row = flat >> 2;
            int k8s = (flat & 3) ^ ((flat >> 3) & 3);
            glds16(L + 4096 + flat * 8, Brow + row * 256 + k0 + k8s * 8);
        }
    };

    f32x4 acc[4][4];
    f32x4 z = {0.f, 0.f, 0.f, 0.f};
#pragma unroll
    for (int mi = 0; mi < 4; ++mi)
#pragma unroll
        for (int ni = 0; ni < 4; ++ni) acc[mi][ni] = z;

    stage(0, 0);
    __syncthreads();
    for (int s = 0; s < 8; ++s) {
        int cur = s & 1;
        if (s < 7) stage(cur ^ 1, s + 1);
        const ushort_t* Ab = sh + cur * 8192;
        const ushort_t* Bb = Ab + 4096;
        bf16x8 af[4], bfr[4];
#pragma unroll
        for (int mi = 0; mi < 4; ++mi)
            af[mi] = *reinterpret_cast<const bf16x8*>(Ab + (wr * 64 + mi * 16 + ln15) * 32 + swz * 8);
#pragma unroll
        for (int ni = 0; ni < 4; ++ni)
            bfr[ni] = *reinterpret_cast<const bf16x8*>(Bb + (wc * 64 + ni * 16 + ln15) * 32 + swz * 8);
#pragma unroll
        for (int mi = 0; mi < 4; ++mi)
#pragma unroll
            for (int ni = 0; ni < 4; ++ni)
                acc[mi][ni] = __builtin_amdgcn_mfma_f32_16x16x32_bf16(af[mi], bfr[ni], acc[mi][ni], 0, 0, 0);
        __syncthreads();
    }

    ushort_t* OT = sh;  // [128 n][136]
#pragma unroll
    for (int mi = 0; mi < 4; ++mi)
#pragma unroll
        for (int ni = 0; ni < 4; ++ni) {
            int t_loc = wr * 64 + mi * 16 + lq * 4;
            int n_loc = wc * 64 + ni * 16 + ln15;
            ushort4 pk;
            pk.x = f2bf(acc[mi][ni][0]);
            pk.y = f2bf(acc[mi][ni][1]);
            pk.z = f2bf(acc[mi][ni][2]);
            pk.w = f2bf(acc[mi][ni][3]);
            *reinterpret_cast<ushort4*>(OT + n_loc * 136 + t_loc) = pk;
        }
    __syncthreads();
    int b = rb >> 4, t0 = (rb & 15) * 128;
#pragma unroll
    for (int jj = 0; jj < 8; ++jj) {
        int flat = tid + jj * 256;
        int n_loc = flat >> 4, te = (flat & 15) * 8;
        int nn = n0 + n_loc;
        int c = nn >> 8, o = nn & 255;
        *reinterpret_cast<u16x8*>(yt + ((size_t)(b * NC + c) * NO + o) * SL + t0 + te) =
            *reinterpret_cast<const u16x8*>(OT + n_loc * 136 + te);
    }
}

// ---- kernel 3: conv, 256x256-tile 8-wave gray-code 4-phase split-K GEMM --
// Phases (QM,QN): (0,0)->(0,1)->(1,1)->(1,0). Register-held fragments:
//   af = A-quadrant (held 2 phases), bv1 (P1-P2), bv0 (P0->P3).
// LDS reads/wave/K-tile: 12+4+8+0 = 24 (was 48).
// Stage issue: P1:B0(s+2) P2:B1(s+2) P3:A0+A1(s+2); all >=1 barrier after
// that region's last read. Boundary: counted vmcnt(8) (16 glds16 in flight).
#define LOAD_A(QM) do {                                                             \
    int arb = wr * 128 + (QM) * 64;                                                 \
    _Pragma("unroll") for (int m = 0; m < 4; ++m) {                                 \
        int row = arb + m * 16 + ln15;                                              \
        _Pragma("unroll") for (int kk = 0; kk < 2; ++kk)                            \
            af[m][kk] = *(const bf16x8*)(Ab + row * 64 + ((kk * 4 + lq) ^ (row & 7)) * 8); \
    }                                                                               \
} while (0)

#define LOAD_B(DST, QN) do {                                                        \
    int brb = wc * 64 + (QN) * 32;                                                  \
    _Pragma("unroll") for (int n2 = 0; n2 < 2; ++n2) {                              \
        int row = brb + n2 * 16 + ln15;                                             \
        _Pragma("unroll") for (int kk = 0; kk < 2; ++kk)                            \
            DST[n2][kk] = *(const bf16x8*)(Bb + row * 64 + ((kk * 4 + lq) ^ (row & 7)) * 8); \
    }                                                                               \
} while (0)

#define MFMAS(QM, QN, BV) do {                                                      \
    _Pragma("unroll") for (int m = 0; m < 4; ++m)                                   \
    _Pragma("unroll") for (int n2 = 0; n2 < 2; ++n2) {                              \
        acc[(QM)*4+m][(QN)*2+n2] = __builtin_amdgcn_mfma_f32_16x16x32_bf16(         \
            af[m][0], BV[n2][0], acc[(QM)*4+m][(QN)*2+n2], 0, 0, 0);                \
        acc[(QM)*4+m][(QN)*2+n2] = __builtin_amdgcn_mfma_f32_16x16x32_bf16(         \
            af[m][1], BV[n2][1], acc[(QM)*4+m][(QN)*2+n2], 0, 0, 0);                \
    }                                                                               \
} while (0)

#define PHASE_TAIL()                                                                \
    __builtin_amdgcn_s_barrier();                                                   \
    asm volatile("s_waitcnt lgkmcnt(0)" ::: "memory");                              \
    __builtin_amdgcn_sched_barrier(0);                                              \
    __builtin_amdgcn_s_setprio(1)

__global__ __launch_bounds__(512, 2) void k_conv8(const ushort_t* __restrict__ Tb,
                                                  const ushort_t* __restrict__ yt,
                                                  float* __restrict__ out) {
    __shared__ ushort_t sh[65536];   // A par0|par1 @0,16384 ; B par0|par1 @32768,49152

    int blk = blockIdx.x;                       // 256
    int orig = (blk & 7) * 32 + (blk >> 3);     // XCD-chunked bijective (256%8==0)
    const int NBt[8] = {4, 7, 11, 14, 18, 21, 25, 28};   // sum = 128 per batch
    int b_ = orig >> 7;
    int j = orig & 127;
    int pp = 0, base = 0;
    while (pp < 7 && j >= base + NBt[pp]) { base += NBt[pp]; ++pp; }
    int idx = j - base, n = NBt[pp];
    int U = 192 * (pp + 1);                     // K-tiles in this group
    int u0 = idx * U / n, u1 = (idx + 1) * U / n;

    int tid = threadIdx.x, lane = tid & 63, wid = tid >> 6;
    int wr = wid >> 2, wc = wid & 3;            // 2M x 4N waves
    int ln15 = lane & 15, lq = lane >> 4;

    const ushort_t* YTb = yt + ((size_t)(b_ * NC * NO) << 11);

    auto stageA = [&](int qm, int u) {
        int tt = u / 48, c = u - tt * 48;
        ushort_t* L = sh + (u & 1) * 16384;
#pragma unroll
        for (int jj = 0; jj < 2; ++jj) {
            int row = jj * 128 + qm * 64 + (tid >> 3);
            int sl = tid & 7;
            int s_idx = 4 * pp + (row >> 6) - tt + 3;
            const ushort_t* src = Tb + (((size_t)(s_idx * NC + c)) << 12)
                                + (row & 63) * 64 + ((sl ^ (row & 7)) * 8);
            glds16(L + row * 64 + sl * 8, src);
        }
    };
    auto stageB = [&](int qn, int u) {
        int tt = u / 48, c = u - tt * 48;
        ushort_t* L = sh + 32768 + (u & 1) * 16384;
#pragma unroll
        for (int jj = 0; jj < 2; ++jj) {
            int rr = tid + jj * 512;
            int ro = rr >> 3, sl = rr & 7;
            int row = (ro >> 5) * 64 + qn * 32 + (ro & 31);
            const ushort_t* src = YTb + (((size_t)(c * NO + row)) << 11)
                                + tt * 64 + ((sl ^ (row & 7)) * 8);
            glds16(L + row * 64 + sl * 8, src);
        }
    };

    f32x4 acc[8][4];
    f32x4 z = {0.f, 0.f, 0.f, 0.f};
#pragma unroll
    for (int mi = 0; mi < 8; ++mi)
#pragma unroll
        for (int ni = 0; ni < 4; ++ni) acc[mi][ni] = z;

    // prologue: all 4 units of u0, then all 4 of u0+1 (u1-u0 >= 6 always)
    stageA(0, u0); stageA(1, u0); stageB(0, u0); stageB(1, u0);
    stageA(0, u0 + 1); stageA(1, u0 + 1); stageB(0, u0 + 1); stageB(1, u0 + 1);
    asm volatile("s_waitcnt vmcnt(8)" ::: "memory");
    __builtin_amdgcn_s_barrier();

    for (int s = u0; s < u1; ++s) {
        const ushort_t* Ab = sh + (s & 1) * 16384;
        const ushort_t* Bb = sh + 32768 + (s & 1) * 16384;
        bf16x8 af[4][2], bv0[2][2], bv1[2][2];

        // P0: read A0+B0 (12); no stage; compute (0,0)
        LOAD_A(0);
        LOAD_B(bv0, 0);
        PHASE_TAIL();
        MFMAS(0, 0, bv0);
        __builtin_amdgcn_s_setprio(0);
        __builtin_amdgcn_s_barrier();

        // P1: read B1 (4); stage B0(s+2); compute (0,1) with held af=A0
        LOAD_B(bv1, 1);
        if (s + 2 < u1) stageB(0, s + 2);
        PHASE_TAIL();
        MFMAS(0, 1, bv1);
        __builtin_amdgcn_s_setprio(0);
        __builtin_amdgcn_s_barrier();

        // P2: read A1 (8, overwrites af); stage B1(s+2); compute (1,1) with held bv1
        LOAD_A(1);
        if (s + 2 < u1) stageB(1, s + 2);
        PHASE_TAIL();
        MFMAS(1, 1, bv1);
        __builtin_amdgcn_s_setprio(0);
        __builtin_amdgcn_s_barrier();

        // P3: no LDS reads; stage A0+A1(s+2); compute (1,0) with held af=A1, bv0
        if (s + 2 < u1) { stageA(0, s + 2); stageA(1, s + 2); }
        __builtin_amdgcn_s_setprio(1);
        MFMAS(1, 0, bv0);
        __builtin_amdgcn_s_setprio(0);
        if (s + 2 < u1) asm volatile("s_waitcnt vmcnt(8)" ::: "memory");
        else            asm volatile("s_waitcnt vmcnt(0)" ::: "memory");
        __builtin_amdgcn_s_barrier();
    }

    float* outp = out + (((size_t)b_ * SL) + (size_t)pp * 256) * NO;
#pragma unroll
    for (int mi = 0; mi < 8; ++mi)
#pragma unroll
        for (int ni = 0; ni < 4; ++ni) {
            int l = wr * 128 + mi * 16 + lq * 4;
            int o = wc * 64 + ni * 16 + ln15;
#pragma unroll
            for (int r = 0; r < 4; ++r)
                atomicAdd(&outp[(size_t)(l + r) * NO + o], acc[mi][ni][r]);
        }
}

extern "C" void kernel_launch(void* const* d_in, const int* in_sizes, int n_in,
                              void* d_out, int out_size, void* d_ws, size_t ws_size,
                              hipStream_t stream) {
    const float* x   = (const float*)d_in[0];
    const float* phi = (const float*)d_in[1];
    const float* Mp  = (const float*)d_in[2];
    const float* Mm  = (const float*)d_in[3];
    float* out = (float*)d_out;

    if (ws_size < WS_NEED) return;

    char* ws = (char*)d_ws;
    ushort_t* T  = (ushort_t*)(ws + OFF_T);
    ushort_t* MT = (ushort_t*)(ws + OFF_MT);
    ushort_t* XB = (ushort_t*)(ws + OFF_XB);
    ushort_t* YT = (ushort_t*)(ws + OFF_YT);

    hipMemsetAsync(d_out, 0, (size_t)out_size * sizeof(float), stream);
    k_cvt_x<<<dim3(262144 / 256), dim3(256), 0, stream>>>(x, XB);
    k_mt<<<dim3(48, 4, 4), dim3(256), 0, stream>>>(Mp, Mm, MT);
    k_toep<<<dim3(35, 48), dim3(64), 0, stream>>>(phi, T);
    k_gemm1<<<dim3(96, 32), dim3(256), 0, stream>>>(XB, MT, YT);
    k_conv8<<<dim3(256), dim3(512), 0, stream>>>(T, YT, out);
}

// Round 6
// 228.406 us; speedup vs baseline: 1.0162x; 1.0162x over previous
//
#include <hip/hip_runtime.h>
#include <hip/hip_bf16.h>

#define SL 2048
#define NK 24
#define NI 256
#define NO 256
#define NB 2
#define NC 48
#define TD 64

typedef __bf16 bf16x8 __attribute__((ext_vector_type(8)));
typedef float f32x4 __attribute__((ext_vector_type(4)));
typedef unsigned short u16x8 __attribute__((ext_vector_type(8)));
typedef unsigned short ushort_t;
typedef unsigned int u32;

// workspace layout (bytes)
// Toeplitz bank: 35 slots (slots 0..2 = zeros for d=-3..-1; slot s=d+3)
#define OFF_T   0ull
#define SZ_T    (35ull*48*64*64*2)
#define OFF_MT  (OFF_T + SZ_T)            // M_T [48][256][256] bf16 ([c][o][i])
#define SZ_MT   (48ull*256*256*2)
#define OFF_XB  (OFF_MT + SZ_MT)          // x bf16 [2][2048][256]
#define SZ_XB   (2ull*2048*256*2)
#define OFF_YT  (OFF_XB + SZ_XB)          // Y_T [2][48][256][2048] bf16 ([b][c][o][t])
#define SZ_YT   (2ull*48*256*2048*2)
#define WS_NEED (OFF_YT + SZ_YT)

__device__ __forceinline__ unsigned short f2bf(float f) {
    unsigned int u = __float_as_uint(f);
    unsigned int r = (u + 0x7FFFu + ((u >> 16) & 1u)) >> 16;
    return (unsigned short)r;
}

__device__ __forceinline__ void glds16(ushort_t* l, const ushort_t* g) {
    __builtin_amdgcn_global_load_lds((const __attribute__((address_space(1))) u32*)g,
                                     (__attribute__((address_space(3))) u32*)l, 16, 0, 0);
}

// ---- kernel 0a: x f32 -> bf16 -------------------------------------------
__global__ void k_cvt_x(const float* __restrict__ x, ushort_t* __restrict__ xb) {
    int i = blockIdx.x * blockDim.x + threadIdx.x;
    float4 v = reinterpret_cast<const float4*>(x)[i];
    ushort4 o;
    o.x = f2bf(v.x); o.y = f2bf(v.y); o.z = f2bf(v.z); o.w = f2bf(v.w);
    reinterpret_cast<ushort4*>(xb)[i] = o;
}

// ---- kernel 0b: M [k][i][o] f32 -> M_T [c][o][i] bf16 -------------------
__global__ void k_mt(const float* __restrict__ Mp, const float* __restrict__ Mm,
                     ushort_t* __restrict__ mt) {
    __shared__ float tile[64][65];
    int c = blockIdx.x, it = blockIdx.y, ot = blockIdx.z;
    int k = c >> 1;
    const float* M = (c & 1) ? Mm : Mp;
    int tid = threadIdx.x;
    int col = tid & 63, rq = tid >> 6;
    for (int rr = 0; rr < 64; rr += 4) {
        int i = rr + rq;
        tile[i][col] = M[((k * NI) + (it * 64 + i)) * NO + ot * 64 + col];
    }
    __syncthreads();
    for (int rr = 0; rr < 64; rr += 4) {
        int o = rr + rq;
        mt[((c * NO) + (ot * 64 + o)) * NI + it * 64 + col] = f2bf(tile[col][o]);
    }
}

// ---- kernel 1: Toeplitz bank, slot s=d+3: T[s][c][li][ti] = F[64d+li-ti, c]
__global__ void k_toep(const float* __restrict__ phi, ushort_t* __restrict__ T) {
    int d = (int)blockIdx.x - 3, c = blockIdx.y;
    int ti = threadIdx.x;
    int k = c >> 1, odd = c & 1;
    for (int li = 0; li < TD; ++li) {
        int s = d * TD + li - ti;
        float v = 0.f;
        if (s >= 0 && s < SL) {
            v = phi[s * NK + k];
            if (odd && (s & 1)) v = -v;
        }
        T[(((blockIdx.x) * NC + c) * TD + li) * TD + ti] = f2bf(v);
    }
}

// ---- kernel 2: Y_T[b][c][o][t] = sum_i x[b,t,i] * M_c[i,o] (known-good) --
__global__ __launch_bounds__(256, 3) void k_gemm1(const ushort_t* __restrict__ XB,
                                                  const ushort_t* __restrict__ MT,
                                                  ushort_t* __restrict__ yt) {
    __shared__ ushort_t sh[17408];
    int nb_ = blockIdx.x;
    int rb  = blockIdx.y;
    int n0 = nb_ * 128;
    int tid = threadIdx.x, lane = tid & 63, wid = tid >> 6;
    int wr = wid >> 1, wc = wid & 1;
    int ln15 = lane & 15, lq = lane >> 4;
    int swz = lq ^ ((ln15 >> 1) & 3);

    const ushort_t* Arow = XB + (size_t)(rb * 128) * 256;
    const ushort_t* Brow = MT + (size_t)n0 * 256;

    auto stage = [&](int bufsel, int s) {
        ushort_t* L = sh + bufsel * 8192;
        int k0 = s * 32;
#pragma unroll
        for (int jj = 0; jj < 2; ++jj) {
            int flat = tid + jj * 256;
            int row = flat >> 2;
            int k8s = (flat & 3) ^ ((flat >> 3) & 3);
            glds16(L + flat * 8, Arow + row * 256 + k0 + k8s * 8);
        }
#pragma unroll
        for (int jj = 0; jj < 2; ++jj) {
            int flat = tid + jj * 256;
            int row = flat >> 2;
            int k8s = (flat & 3) ^ ((flat >> 3) & 3);
            glds16(L + 4096 + flat * 8, Brow + row * 256 + k0 + k8s * 8);
        }
    };

    f32x4 acc[4][4];
    f32x4 z = {0.f, 0.f, 0.f, 0.f};
#pragma unroll
    for (int mi = 0; mi < 4; ++mi)
#pragma unroll
        for (int ni = 0; ni < 4; ++ni) acc[mi][ni] = z;

    stage(0, 0);
    __syncthreads();
    for (int s = 0; s < 8; ++s) {
        int cur = s & 1;
        if (s < 7) stage(cur ^ 1, s + 1);
        const ushort_t* Ab = sh + cur * 8192;
        const ushort_t* Bb = Ab + 4096;
        bf16x8 af[4], bfr[4];
#pragma unroll
        for (int mi = 0; mi < 4; ++mi)
            af[mi] = *reinterpret_cast<const bf16x8*>(Ab + (wr * 64 + mi * 16 + ln15) * 32 + swz * 8);
#pragma unroll
        for (int ni = 0; ni < 4; ++ni)
            bfr[ni] = *reinterpret_cast<const bf16x8*>(Bb + (wc * 64 + ni * 16 + ln15) * 32 + swz * 8);
#pragma unroll
        for (int mi = 0; mi < 4; ++mi)
#pragma unroll
            for (int ni = 0; ni < 4; ++ni)
                acc[mi][ni] = __builtin_amdgcn_mfma_f32_16x16x32_bf16(af[mi], bfr[ni], acc[mi][ni], 0, 0, 0);
        __syncthreads();
    }

    ushort_t* OT = sh;  // [128 n][136]
#pragma unroll
    for (int mi = 0; mi < 4; ++mi)
#pragma unroll
        for (int ni = 0; ni < 4; ++ni) {
            int t_loc = wr * 64 + mi * 16 + lq * 4;
            int n_loc = wc * 64 + ni * 16 + ln15;
            ushort4 pk;
            pk.x = f2bf(acc[mi][ni][0]);
            pk.y = f2bf(acc[mi][ni][1]);
            pk.z = f2bf(acc[mi][ni][2]);
            pk.w = f2bf(acc[mi][ni][3]);
            *reinterpret_cast<ushort4*>(OT + n_loc * 136 + t_loc) = pk;
        }
    __syncthreads();
    int b = rb >> 4, t0 = (rb & 15) * 128;
#pragma unroll
    for (int jj = 0; jj < 8; ++jj) {
        int flat = tid + jj * 256;
        int n_loc = flat >> 4, te = (flat & 15) * 8;
        int nn = n0 + n_loc;
        int c = nn >> 8, o = nn & 255;
        *reinterpret_cast<u16x8*>(yt + ((size_t)(b * NC + c) * NO + o) * SL + t0 + te) =
            *reinterpret_cast<const u16x8*>(OT + n_loc * 136 + te);
    }
}

// ---- kernel 3: conv, 256x256-tile split-K GEMM, overlapped 2-barrier tile -
// Per K-tile(64): [24 ds_read -> 4 frag sets (compiler fine-grained lgkm)]
//   [MFMA Q00,Q01 overlap a1/b1 LDS service] [lgkm(0); barrier]
//   [issue 8 glds16 for s+2 into SAME buffer (readers all done)] [MFMA Q11,Q10]
//   [vmcnt(8); barrier]. All per-lane addressing hoisted out of the loop.
#define LOAD_A(DST, QM, AB) do {                                                   \
    _Pragma("unroll") for (int m = 0; m < 4; ++m) {                                \
        DST[m][0] = *(const bf16x8*)((AB) + aB0 + (QM) * 8192 + m * 2048);         \
        DST[m][1] = *(const bf16x8*)((AB) + aB1 + (QM) * 8192 + m * 2048);         \
    }                                                                              \
} while (0)

#define LOAD_B(DST, QN, BB) do {                                                   \
    _Pragma("unroll") for (int n2 = 0; n2 < 2; ++n2) {                             \
        DST[n2][0] = *(const bf16x8*)((BB) + bB0 + (QN) * 4096 + n2 * 2048);       \
        DST[n2][1] = *(const bf16x8*)((BB) + bB1 + (QN) * 4096 + n2 * 2048);       \
    }                                                                              \
} while (0)

#define MFMAS(QM, QN, AF, BV) do {                                                 \
    _Pragma("unroll") for (int m = 0; m < 4; ++m)                                  \
    _Pragma("unroll") for (int n2 = 0; n2 < 2; ++n2) {                             \
        acc[(QM)*4+m][(QN)*2+n2] = __builtin_amdgcn_mfma_f32_16x16x32_bf16(        \
            AF[m][0], BV[n2][0], acc[(QM)*4+m][(QN)*2+n2], 0, 0, 0);               \
        acc[(QM)*4+m][(QN)*2+n2] = __builtin_amdgcn_mfma_f32_16x16x32_bf16(        \
            AF[m][1], BV[n2][1], acc[(QM)*4+m][(QN)*2+n2], 0, 0, 0);               \
    }                                                                              \
} while (0)

__global__ __launch_bounds__(512, 2) void k_conv8(const ushort_t* __restrict__ Tb,
                                                  const ushort_t* __restrict__ yt,
                                                  float* __restrict__ out) {
    __shared__ ushort_t sh[65536];   // A bufs @ bytes 0/32768 ; B bufs @ 65536/98304

    int blk = blockIdx.x;                       // 256
    int orig = (blk & 7) * 32 + (blk >> 3);     // XCD-chunked bijective (256%8==0)
    const int NBt[8] = {4, 7, 11, 14, 18, 21, 25, 28};   // sum = 128 per batch
    int b_ = orig >> 7;
    int j = orig & 127;
    int pp = 0, base = 0;
    while (pp < 7 && j >= base + NBt[pp]) { base += NBt[pp]; ++pp; }
    int idx = j - base, n = NBt[pp];
    int U = 192 * (pp + 1);                     // K-tiles in this group
    int u0 = idx * U / n, u1 = (idx + 1) * U / n;

    int tid = threadIdx.x, lane = tid & 63, wid = tid >> 6;
    int wr = wid >> 2, wc = wid & 3;            // 2M x 4N waves
    int ln15 = lane & 15, lq = lane >> 4;

    const ushort_t* YTb = yt + ((size_t)(b_ * NC * NO) << 11);
    const char* shc = (const char*)sh;

    // hoisted per-lane constants -------------------------------------------
    int s0l = (lq ^ (ln15 & 7)) * 16;           // swizzled 16B slot, kk=0 (bytes)
    int s1l = ((4 + lq) ^ (ln15 & 7)) * 16;     // kk=1
    int aB0 = (wr * 128 + ln15) * 128 + s0l;    // A frag base (bytes in A tile)
    int aB1 = (wr * 128 + ln15) * 128 + s1l;
    int bB0 = (wc * 64 + ln15) * 128 + s0l;     // B frag base
    int bB1 = (wc * 64 + ln15) * 128 + s1l;
    int gAl = (tid >> 3) * 64 + ((tid & 7) ^ ((tid >> 3) & 7)) * 8;          // elems
    int gBl = ((tid >> 3) & 31) * 2048 + ((tid & 7) ^ ((tid >> 3) & 7)) * 8; // elems
    int w2  = wid >> 2;
    int dAl = tid * 8;                                        // A LDS dest (elems)
    int dBl = w2 * 4096 + (wid & 3) * 512 + lane * 8;         // B LDS dest (elems)

    auto stageA = [&](ushort_t* L, int tt, int c) {
#pragma unroll
        for (int jj = 0; jj < 2; ++jj)
#pragma unroll
            for (int qm = 0; qm < 2; ++qm) {
                int slot = 4 * pp + jj * 2 + qm - tt + 3;
                glds16(L + jj * 8192 + qm * 4096 + dAl,
                       Tb + (((size_t)(slot * NC + c)) << 12) + gAl);
            }
    };
    auto stageB = [&](ushort_t* L, int tt, int c) {
#pragma unroll
        for (int jj = 0; jj < 2; ++jj)
#pragma unroll
            for (int qn = 0; qn < 2; ++qn) {
                int rowS = (jj * 2 + w2) * 64 + qn * 32;
                glds16(L + jj * 8192 + qn * 2048 + dBl,
                       YTb + (((size_t)(c * NO + rowS)) << 11) + tt * 64 + gBl);
            }
    };

    f32x4 acc[8][4];
    f32x4 z = {0.f, 0.f, 0.f, 0.f};
#pragma unroll
    for (int mi = 0; mi < 8; ++mi)
#pragma unroll
        for (int ni = 0; ni < 4; ++ni) acc[mi][ni] = z;

    // prologue: stage u0 and u0+1
    {
        int tt0 = u0 / 48, c0 = u0 - tt0 * 48;
        stageA(sh + ((u0 & 1) << 14), tt0, c0);
        stageB(sh + 32768 + ((u0 & 1) << 14), tt0, c0);
        int uu = u0 + 1;
        int tt1 = uu / 48, c1 = uu - tt1 * 48;
        stageA(sh + ((uu & 1) << 14), tt1, c1);
        stageB(sh + 32768 + ((uu & 1) << 14), tt1, c1);
    }
    asm volatile("s_waitcnt vmcnt(8)" ::: "memory");
    asm volatile("s_barrier" ::: "memory");

    for (int s = u0; s < u1; ++s) {
        const char* AB = shc + ((s & 1) << 15);
        const char* BB = shc + 65536 + ((s & 1) << 15);
        bf16x8 a0[4][2], a1[4][2], b0[2][2], b1[2][2];
        // tile-top: all 24 ds_reads (compiler inserts fine-grained lgkm waits)
        LOAD_A(a0, 0, AB);
        LOAD_B(b0, 0, BB);
        LOAD_B(b1, 1, BB);
        LOAD_A(a1, 1, AB);

        __builtin_amdgcn_s_setprio(1);
        MFMAS(0, 0, a0, b0);
        MFMAS(0, 1, a0, b1);
        __builtin_amdgcn_s_setprio(0);

        // all reads complete before anyone's stage-writes can land
        asm volatile("s_waitcnt lgkmcnt(0)" ::: "memory");
        __builtin_amdgcn_sched_barrier(0);
        asm volatile("s_barrier" ::: "memory");

        int u2 = s + 2;
        if (u2 < u1) {
            int tt2 = u2 / 48, c2 = u2 - tt2 * 48;
            ushort_t* LA = sh + ((u2 & 1) << 14);
            ushort_t* LB = sh + 32768 + ((u2 & 1) << 14);
            stageA(LA, tt2, c2);
            stageB(LB, tt2, c2);
        }

        __builtin_amdgcn_s_setprio(1);
        MFMAS(1, 1, a1, b1);
        MFMAS(1, 0, a1, b0);
        __builtin_amdgcn_s_setprio(0);

        if (u2 < u1) asm volatile("s_waitcnt vmcnt(8)" ::: "memory");
        else         asm volatile("s_waitcnt vmcnt(0)" ::: "memory");
        __builtin_amdgcn_sched_barrier(0);
        asm volatile("s_barrier" ::: "memory");
    }

    float* outp = out + (((size_t)b_ * SL) + (size_t)pp * 256) * NO;
#pragma unroll
    for (int mi = 0; mi < 8; ++mi)
#pragma unroll
        for (int ni = 0; ni < 4; ++ni) {
            int l = wr * 128 + mi * 16 + lq * 4;
            int o = wc * 64 + ni * 16 + ln15;
#pragma unroll
            for (int r = 0; r < 4; ++r)
                atomicAdd(&outp[(size_t)(l + r) * NO + o], acc[mi][ni][r]);
        }
}

extern "C" void kernel_launch(void* const* d_in, const int* in_sizes, int n_in,
                              void* d_out, int out_size, void* d_ws, size_t ws_size,
                              hipStream_t stream) {
    const float* x   = (const float*)d_in[0];
    const float* phi = (const float*)d_in[1];
    const float* Mp  = (const float*)d_in[2];
    const float* Mm  = (const float*)d_in[3];
    float* out = (float*)d_out;

    if (ws_size < WS_NEED) return;

    char* ws = (char*)d_ws;
    ushort_t* T  = (ushort_t*)(ws + OFF_T);
    ushort_t* MT = (ushort_t*)(ws + OFF_MT);
    ushort_t* XB = (ushort_t*)(ws + OFF_XB);
    ushort_t* YT = (ushort_t*)(ws + OFF_YT);

    hipMemsetAsync(d_out, 0, (size_t)out_size * sizeof(float), stream);
    k_cvt_x<<<dim3(262144 / 256), dim3(256), 0, stream>>>(x, XB);
    k_mt<<<dim3(48, 4, 4), dim3(256), 0, stream>>>(Mp, Mm, MT);
    k_toep<<<dim3(35, 48), dim3(64), 0, stream>>>(phi, T);
    k_gemm1<<<dim3(96, 32), dim3(256), 0, stream>>>(XB, MT, YT);
    k_conv8<<<dim3(256), dim3(512), 0, stream>>>(T, YT, out);
}

// Round 7
// 222.017 us; speedup vs baseline: 1.0454x; 1.0288x over previous
//
#include <hip/hip_runtime.h>
#include <hip/hip_bf16.h>

#define SL 2048
#define NK 24
#define NI 256
#define NO 256
#define NB 2
#define NC 48
#define TD 64

typedef __bf16 bf16x8 __attribute__((ext_vector_type(8)));
typedef float f32x4 __attribute__((ext_vector_type(4)));
typedef unsigned short u16x8 __attribute__((ext_vector_type(8)));
typedef unsigned short ushort_t;
typedef unsigned int u32;

// workspace layout (bytes)
// Toeplitz bank: 35 slots (slots 0..2 = zeros for d=-3..-1; slot s=d+3)
#define OFF_T   0ull
#define SZ_T    (35ull*48*64*64*2)
#define OFF_MT  (OFF_T + SZ_T)            // M_T [48][256][256] bf16 ([c][o][i])
#define SZ_MT   (48ull*256*256*2)
#define OFF_XB  (OFF_MT + SZ_MT)          // x bf16 [2][2048][256]
#define SZ_XB   (2ull*2048*256*2)
#define OFF_YT  (OFF_XB + SZ_XB)          // Y_T [2][48][256][2048] bf16 ([b][c][o][t])
#define SZ_YT   (2ull*48*256*2048*2)
#define WS_NEED (OFF_YT + SZ_YT)

__device__ __forceinline__ unsigned short f2bf(float f) {
    unsigned int u = __float_as_uint(f);
    unsigned int r = (u + 0x7FFFu + ((u >> 16) & 1u)) >> 16;
    return (unsigned short)r;
}

__device__ __forceinline__ void glds16(ushort_t* l, const ushort_t* g) {
    __builtin_amdgcn_global_load_lds((const __attribute__((address_space(1))) u32*)g,
                                     (__attribute__((address_space(3))) u32*)l, 16, 0, 0);
}

// ---- kernel 0a: x f32 -> bf16 -------------------------------------------
__global__ void k_cvt_x(const float* __restrict__ x, ushort_t* __restrict__ xb) {
    int i = blockIdx.x * blockDim.x + threadIdx.x;
    float4 v = reinterpret_cast<const float4*>(x)[i];
    ushort4 o;
    o.x = f2bf(v.x); o.y = f2bf(v.y); o.z = f2bf(v.z); o.w = f2bf(v.w);
    reinterpret_cast<ushort4*>(xb)[i] = o;
}

// ---- kernel 0b: M [k][i][o] f32 -> M_T [c][o][i] bf16 -------------------
__global__ void k_mt(const float* __restrict__ Mp, const float* __restrict__ Mm,
                     ushort_t* __restrict__ mt) {
    __shared__ float tile[64][65];
    int c = blockIdx.x, it = blockIdx.y, ot = blockIdx.z;
    int k = c >> 1;
    const float* M = (c & 1) ? Mm : Mp;
    int tid = threadIdx.x;
    int col = tid & 63, rq = tid >> 6;
    for (int rr = 0; rr < 64; rr += 4) {
        int i = rr + rq;
        tile[i][col] = M[((k * NI) + (it * 64 + i)) * NO + ot * 64 + col];
    }
    __syncthreads();
    for (int rr = 0; rr < 64; rr += 4) {
        int o = rr + rq;
        mt[((c * NO) + (ot * 64 + o)) * NI + it * 64 + col] = f2bf(tile[col][o]);
    }
}

// ---- kernel 1: Toeplitz bank, slot s=d+3: T[s][c][li][ti] = F[64d+li-ti, c]
__global__ void k_toep(const float* __restrict__ phi, ushort_t* __restrict__ T) {
    int d = (int)blockIdx.x - 3, c = blockIdx.y;
    int ti = threadIdx.x;
    int k = c >> 1, odd = c & 1;
    for (int li = 0; li < TD; ++li) {
        int s = d * TD + li - ti;
        float v = 0.f;
        if (s >= 0 && s < SL) {
            v = phi[s * NK + k];
            if (odd && (s & 1)) v = -v;
        }
        T[(((blockIdx.x) * NC + c) * TD + li) * TD + ti] = f2bf(v);
    }
}

// ---- kernel 2: Y_T[b][c][o][t] = sum_i x[b,t,i] * M_c[i,o] (known-good) --
__global__ __launch_bounds__(256, 3) void k_gemm1(const ushort_t* __restrict__ XB,
                                                  const ushort_t* __restrict__ MT,
                                                  ushort_t* __restrict__ yt) {
    __shared__ ushort_t sh[17408];
    int nb_ = blockIdx.x;
    int rb  = blockIdx.y;
    int n0 = nb_ * 128;
    int tid = threadIdx.x, lane = tid & 63, wid = tid >> 6;
    int wr = wid >> 1, wc = wid & 1;
    int ln15 = lane & 15, lq = lane >> 4;
    int swz = lq ^ ((ln15 >> 1) & 3);

    const ushort_t* Arow = XB + (size_t)(rb * 128) * 256;
    const ushort_t* Brow = MT + (size_t)n0 * 256;

    auto stage = [&](int bufsel, int s) {
        ushort_t* L = sh + bufsel * 8192;
        int k0 = s * 32;
#pragma unroll
        for (int jj = 0; jj < 2; ++jj) {
            int flat = tid + jj * 256;
            int row = flat >> 2;
            int k8s = (flat & 3) ^ ((flat >> 3) & 3);
            glds16(L + flat * 8, Arow + row * 256 + k0 + k8s * 8);
        }
#pragma unroll
        for (int jj = 0; jj < 2; ++jj) {
            int flat = tid + jj * 256;
            int row = flat >> 2;
            int k8s = (flat & 3) ^ ((flat >> 3) & 3);
            glds16(L + 4096 + flat * 8, Brow + row * 256 + k0 + k8s * 8);
        }
    };

    f32x4 acc[4][4];
    f32x4 z = {0.f, 0.f, 0.f, 0.f};
#pragma unroll
    for (int mi = 0; mi < 4; ++mi)
#pragma unroll
        for (int ni = 0; ni < 4; ++ni) acc[mi][ni] = z;

    stage(0, 0);
    __syncthreads();
    for (int s = 0; s < 8; ++s) {
        int cur = s & 1;
        if (s < 7) stage(cur ^ 1, s + 1);
        const ushort_t* Ab = sh + cur * 8192;
        const ushort_t* Bb = Ab + 4096;
        bf16x8 af[4], bfr[4];
#pragma unroll
        for (int mi = 0; mi < 4; ++mi)
            af[mi] = *reinterpret_cast<const bf16x8*>(Ab + (wr * 64 + mi * 16 + ln15) * 32 + swz * 8);
#pragma unroll
        for (int ni = 0; ni < 4; ++ni)
            bfr[ni] = *reinterpret_cast<const bf16x8*>(Bb + (wc * 64 + ni * 16 + ln15) * 32 + swz * 8);
#pragma unroll
        for (int mi = 0; mi < 4; ++mi)
#pragma unroll
            for (int ni = 0; ni < 4; ++ni)
                acc[mi][ni] = __builtin_amdgcn_mfma_f32_16x16x32_bf16(af[mi], bfr[ni], acc[mi][ni], 0, 0, 0);
        __syncthreads();
    }

    ushort_t* OT = sh;  // [128 n][136]
#pragma unroll
    for (int mi = 0; mi < 4; ++mi)
#pragma unroll
        for (int ni = 0; ni < 4; ++ni) {
            int t_loc = wr * 64 + mi * 16 + lq * 4;
            int n_loc = wc * 64 + ni * 16 + ln15;
            ushort4 pk;
            pk.x = f2bf(acc[mi][ni][0]);
            pk.y = f2bf(acc[mi][ni][1]);
            pk.z = f2bf(acc[mi][ni][2]);
            pk.w = f2bf(acc[mi][ni][3]);
            *reinterpret_cast<ushort4*>(OT + n_loc * 136 + t_loc) = pk;
        }
    __syncthreads();
    int b = rb >> 4, t0 = (rb & 15) * 128;
#pragma unroll
    for (int jj = 0; jj < 8; ++jj) {
        int flat = tid + jj * 256;
        int n_loc = flat >> 4, te = (flat & 15) * 8;
        int nn = n0 + n_loc;
        int c = nn >> 8, o = nn & 255;
        *reinterpret_cast<u16x8*>(yt + ((size_t)(b * NC + c) * NO + o) * SL + t0 + te) =
            *reinterpret_cast<const u16x8*>(OT + n_loc * 136 + te);
    }
}

// ---- kernel 3: conv, 256x256-tile split-K GEMM, cross-tile reg pipeline --
// Half-K-tile (K=32) register double-buffer: tile s's MFMAs consume frags
// loaded during tile s-1 / earlier in tile s, overlapping LDS service with
// the matrix pipe. ONE barrier + one lgkm(0) + one vmcnt(0of8) per K-tile.
//   per tile s: [reads h1->set1][MFMA h0(set0)][lgkm0;vmcnt0][barrier]
//               [stage s+2][reads h0(s+1)->set0][MFMA h1(set1)]
#define LOAD_SET(SA, SB, SLOT, AB, BB) do {                                        \
    _Pragma("unroll") for (int m = 0; m < 8; ++m)                                  \
        SA[m] = *(const bf16x8*)((AB) + aBase + (SLOT) + m * 2048);                \
    _Pragma("unroll") for (int n2 = 0; n2 < 4; ++n2)                               \
        SB[n2] = *(const bf16x8*)((BB) + bBase + (SLOT) + n2 * 2048);              \
} while (0)

#define MFMA_SET(SA, SB) do {                                                      \
    _Pragma("unroll") for (int m = 0; m < 8; ++m)                                  \
    _Pragma("unroll") for (int n2 = 0; n2 < 4; ++n2)                               \
        acc[m][n2] = __builtin_amdgcn_mfma_f32_16x16x32_bf16(                      \
            SA[m], SB[n2], acc[m][n2], 0, 0, 0);                                   \
} while (0)

__global__ __launch_bounds__(512, 2) void k_conv8(const ushort_t* __restrict__ Tb,
                                                  const ushort_t* __restrict__ yt,
                                                  float* __restrict__ out) {
    __shared__ ushort_t sh[65536];   // A bufs @ bytes 0/32768 ; B bufs @ 65536/98304

    int blk = blockIdx.x;                       // 256
    int orig = (blk & 7) * 32 + (blk >> 3);     // XCD-chunked bijective (256%8==0)
    const int NBt[8] = {4, 7, 11, 14, 18, 21, 25, 28};   // sum = 128 per batch
    int b_ = orig >> 7;
    int j = orig & 127;
    int pp = 0, base = 0;
    while (pp < 7 && j >= base + NBt[pp]) { base += NBt[pp]; ++pp; }
    int idx = j - base, n = NBt[pp];
    int U = 192 * (pp + 1);                     // K-tiles in this group
    int u0 = idx * U / n, u1 = (idx + 1) * U / n;

    int tid = threadIdx.x, lane = tid & 63, wid = tid >> 6;
    int wr = wid >> 2, wc = wid & 3;            // 2M x 4N waves
    int ln15 = lane & 15, lq = lane >> 4;

    const ushort_t* YTb = yt + ((size_t)(b_ * NC * NO) << 11);
    const char* shc = (const char*)sh;

    // hoisted per-lane constants -------------------------------------------
    int s0l = (lq ^ (ln15 & 7)) * 16;           // swizzled 16B slot, kk=0 (bytes)
    int s1l = ((4 + lq) ^ (ln15 & 7)) * 16;     // kk=1
    int aBase = (wr * 128 + ln15) * 128;        // A frag row base (bytes)
    int bBase = (wc * 64 + ln15) * 128;         // B frag row base (bytes)
    int gAl = (tid >> 3) * 64 + ((tid & 7) ^ ((tid >> 3) & 7)) * 8;          // elems
    int gBl = ((tid >> 3) & 31) * 2048 + ((tid & 7) ^ ((tid >> 3) & 7)) * 8; // elems
    int w2  = wid >> 2;
    int dAl = tid * 8;                                        // A LDS dest (elems)
    int dBl = w2 * 4096 + (wid & 3) * 512 + lane * 8;         // B LDS dest (elems)

    auto stageA = [&](ushort_t* L, int tt, int c) {
#pragma unroll
        for (int jj = 0; jj < 2; ++jj)
#pragma unroll
            for (int qm = 0; qm < 2; ++qm) {
                int slot = 4 * pp + jj * 2 + qm - tt + 3;
                glds16(L + jj * 8192 + qm * 4096 + dAl,
                       Tb + (((size_t)(slot * NC + c)) << 12) + gAl);
            }
    };
    auto stageB = [&](ushort_t* L, int tt, int c) {
#pragma unroll
        for (int jj = 0; jj < 2; ++jj)
#pragma unroll
            for (int qn = 0; qn < 2; ++qn) {
                int rowS = (jj * 2 + w2) * 64 + qn * 32;
                glds16(L + jj * 8192 + qn * 2048 + dBl,
                       YTb + (((size_t)(c * NO + rowS)) << 11) + tt * 64 + gBl);
            }
    };
    auto stageU = [&](int u) {
        int tt = u / 48, c = u - tt * 48;
        stageA(sh + ((u & 1) << 14), tt, c);
        stageB(sh + 32768 + ((u & 1) << 14), tt, c);
    };

    f32x4 acc[8][4];
    f32x4 z = {0.f, 0.f, 0.f, 0.f};
#pragma unroll
    for (int mi = 0; mi < 8; ++mi)
#pragma unroll
        for (int ni = 0; ni < 4; ++ni) acc[mi][ni] = z;

    bf16x8 s0a[8], s0b[4], s1a[8], s1b[4];

    // prologue: stage u0, u0+1; confirm u0; load h0(u0) -> set0
    stageU(u0);
    stageU(u0 + 1);
    asm volatile("s_waitcnt vmcnt(8)" ::: "memory");
    asm volatile("s_barrier" ::: "memory");
    {
        const char* AB = shc + ((u0 & 1) << 15);
        const char* BB = shc + 65536 + ((u0 & 1) << 15);
        LOAD_SET(s0a, s0b, s0l, AB, BB);
    }

    for (int s = u0; s < u1; ++s) {
        const char* AB = shc + ((s & 1) << 15);
        const char* BB = shc + 65536 + ((s & 1) << 15);

        // (1) reads h1 -> set1 (service overlaps h0 MFMAs)
        LOAD_SET(s1a, s1b, s1l, AB, BB);
        __builtin_amdgcn_sched_barrier(0);

        // (2) MFMA h0 (set0; loaded during previous tile — compiler-precise lgkm)
        __builtin_amdgcn_s_setprio(1);
        MFMA_SET(s0a, s0b);
        __builtin_amdgcn_s_setprio(0);

        // (3) buffer-release: all my LDS reads of buf(s&1) done; my stage-writes
        //     for s+1 (issued last tile) landed.
        asm volatile("s_waitcnt lgkmcnt(0)" ::: "memory");
        asm volatile("s_waitcnt vmcnt(0)" ::: "memory");
        __builtin_amdgcn_sched_barrier(0);
        // (4) the one barrier: after it, buf(s&1) is writable, buf(s+1) readable
        asm volatile("s_barrier" ::: "memory");

        // (5) stage s+2 into buf(s&1)
        if (s + 2 < u1) stageU(s + 2);

        // (6) reads h0(s+1) -> set0 (service overlaps h1 MFMAs)
        if (s + 1 < u1) {
            const char* AB2 = shc + (((s + 1) & 1) << 15);
            const char* BB2 = shc + 65536 + (((s + 1) & 1) << 15);
            LOAD_SET(s0a, s0b, s0l, AB2, BB2);
        }
        __builtin_amdgcn_sched_barrier(0);

        // (7) MFMA h1 (set1)
        __builtin_amdgcn_s_setprio(1);
        MFMA_SET(s1a, s1b);
        __builtin_amdgcn_s_setprio(0);
        __builtin_amdgcn_sched_barrier(0);
    }

    float* outp = out + (((size_t)b_ * SL) + (size_t)pp * 256) * NO;
#pragma unroll
    for (int mi = 0; mi < 8; ++mi)
#pragma unroll
        for (int ni = 0; ni < 4; ++ni) {
            int l = wr * 128 + mi * 16 + lq * 4;
            int o = wc * 64 + ni * 16 + ln15;
#pragma unroll
            for (int r = 0; r < 4; ++r)
                atomicAdd(&outp[(size_t)(l + r) * NO + o], acc[mi][ni][r]);
        }
}

extern "C" void kernel_launch(void* const* d_in, const int* in_sizes, int n_in,
                              void* d_out, int out_size, void* d_ws, size_t ws_size,
                              hipStream_t stream) {
    const float* x   = (const float*)d_in[0];
    const float* phi = (const float*)d_in[1];
    const float* Mp  = (const float*)d_in[2];
    const float* Mm  = (const float*)d_in[3];
    float* out = (float*)d_out;

    if (ws_size < WS_NEED) return;

    char* ws = (char*)d_ws;
    ushort_t* T  = (ushort_t*)(ws + OFF_T);
    ushort_t* MT = (ushort_t*)(ws + OFF_MT);
    ushort_t* XB = (ushort_t*)(ws + OFF_XB);
    ushort_t* YT = (ushort_t*)(ws + OFF_YT);

    hipMemsetAsync(d_out, 0, (size_t)out_size * sizeof(float), stream);
    k_cvt_x<<<dim3(262144 / 256), dim3(256), 0, stream>>>(x, XB);
    k_mt<<<dim3(48, 4, 4), dim3(256), 0, stream>>>(Mp, Mm, MT);
    k_toep<<<dim3(35, 48), dim3(64), 0, stream>>>(phi, T);
    k_gemm1<<<dim3(96, 32), dim3(256), 0, stream>>>(XB, MT, YT);
    k_conv8<<<dim3(256), dim3(512), 0, stream>>>(T, YT, out);
}